// Round 10
// baseline (832.247 us; speedup 1.0000x reference)
//
#include <hip/hip_runtime.h>
#include <hip/hip_bf16.h>
#include <stdint.h>

#define N_NODES 50000
#define N_EDGES 800000
#define NC3 150000               // 3 graphs x 50k counters
#define NB3 586                  // ceil(150000/256)
#define MG 3125                  // N_NODES/16 m-tiles
#define EG 3125                  // N_EDGES/256 edge blocks

typedef __attribute__((ext_vector_type(8))) short short8;
typedef __attribute__((ext_vector_type(4))) float floatx4;

__device__ __forceinline__ float bfbits2f(unsigned int u16) {
    union { unsigned int i; float f; } c; c.i = u16 << 16; return c.f;
}
__device__ __forceinline__ unsigned short f2bfbits(float f) {
    union { float f; unsigned int i; } c; c.f = f;
    unsigned int r = c.i + 0x7fffu + ((c.i >> 16) & 1u);   // RNE
    return (unsigned short)(r >> 16);
}
__device__ __forceinline__ void acc8(float* a, uint4 v) {
    a[0] += bfbits2f(v.x & 0xffffu); a[1] += bfbits2f(v.x >> 16);
    a[2] += bfbits2f(v.y & 0xffffu); a[3] += bfbits2f(v.y >> 16);
    a[4] += bfbits2f(v.z & 0xffffu); a[5] += bfbits2f(v.z >> 16);
    a[6] += bfbits2f(v.w & 0xffffu); a[7] += bfbits2f(v.w >> 16);
}

// ---- mega1: per-block local dtype detect + weight/bias prep + x->bf16 + count3 (r9-verified) ----
__global__ __launch_bounds__(256) void mega1(
    const void* __restrict__ Wl0, const void* __restrict__ Wr0,
    const void* __restrict__ Wl1, const void* __restrict__ Wr1,
    const void* __restrict__ Wl2, const void* __restrict__ Wr2,
    const void* __restrict__ b0, const void* __restrict__ b1, const void* __restrict__ b2,
    unsigned short* __restrict__ wt,
    const void* __restrict__ x, unsigned short* __restrict__ xb,
    const int* __restrict__ e0, const int* __restrict__ e1, const int* __restrict__ e2,
    int* __restrict__ rp3, int* __restrict__ flagsOut)
{
    __shared__ int s_cnt[2];
    const int t = threadIdx.x;
    if (t < 2) s_cnt[t] = 0;
    __syncthreads();
    {   // local detect (r2-verified logic)
        unsigned short v = ((const unsigned short*)x)[2 * t];
        int ex = (v >> 7) & 0xff;
        if (v == 0 || (ex >= 96 && ex <= 150)) atomicAdd(&s_cnt[0], 1);
        if (e0[2 * t + 1] != 0) atomicAdd(&s_cnt[1], 1);
    }
    __syncthreads();
    const int f0 = (s_cnt[0] < 200) ? 1 : 0;
    const int f1 = (s_cnt[1] < 128) ? 1 : 0;
    const int bid = blockIdx.x;

    if (bid == 16652) {
        if (t == 0) { flagsOut[0] = f0; flagsOut[1] = f1; }
        return;
    }
    if (bid >= 7277) {                       // count3
        int i = (bid - 7277) * 256 + t;
        int g = i / N_EDGES;
        int il = i - g * N_EDGES;
        const int* e = (g == 0) ? e0 : (g == 1) ? e1 : e2;
        int dst = f1 ? e[2 * (N_EDGES + il)] : e[N_EDGES + il];
        atomicAdd(&rp3[g * N_NODES + dst], 1);
        return;
    }
    if (bid >= 1027) {                       // cvt_x
        int i = (bid - 1027) * 256 + t;
        if (f0) {
            float4 v = ((const float4*)x)[i];
            uint2 o;
            o.x = (unsigned int)f2bfbits(v.x) | ((unsigned int)f2bfbits(v.y) << 16);
            o.y = (unsigned int)f2bfbits(v.z) | ((unsigned int)f2bfbits(v.w) << 16);
            ((uint2*)xb)[i] = o;
        } else {
            ((uint2*)xb)[i] = ((const uint2*)x)[i];
        }
        return;
    }
    if (bid >= 1024) {                       // biases
        const void* bs = bid == 1024 ? b0 : (bid == 1025 ? b1 : b2);
        unsigned short* bd = wt + 262144 + (bid - 1024) * 256;
        int n = (bid == 1026) ? 128 : 256;
        if (t < n) bd[t] = f0 ? f2bfbits(((const float*)bs)[t]) : ((const unsigned short*)bs)[t];
        return;
    }
    const void* W; unsigned short* WT; int K, N, off;
    if (bid < 128)      { W = Wl0; WT = wt;          K = 128; N = 256; off = bid; }
    else if (bid < 256) { W = Wr0; WT = wt + 32768;  K = 128; N = 256; off = bid - 128; }
    else if (bid < 512) { W = Wl1; WT = wt + 65536;  K = 256; N = 256; off = bid - 256; }
    else if (bid < 768) { W = Wr1; WT = wt + 131072; K = 256; N = 256; off = bid - 512; }
    else if (bid < 896) { W = Wl2; WT = wt + 196608; K = 256; N = 128; off = bid - 768; }
    else                { W = Wr2; WT = wt + 229376; K = 256; N = 128; off = bid - 896; }
    int idx = off * 256 + t;
    int k = idx / N, n = idx - k * N;
    unsigned short v = f0 ? f2bfbits(((const float*)W)[idx]) : ((const unsigned short*)W)[idx];
    WT[n * K + k] = v;
}

// ---- scan12 (r9-verified): local scan + last-block global partial scan ----
__global__ __launch_bounds__(256) void scan12(
    int* __restrict__ rp3, int* __restrict__ part, int* __restrict__ ticket)
{
    __shared__ int sa[256], sb[256];
    __shared__ int lastBlk;
    const int b = blockIdx.x, t = threadIdx.x, idx = b * 256 + t;
    int v = (idx < NC3) ? rp3[idx] : 0;
    sa[t] = v;
    __syncthreads();
    bool par = true;
#pragma unroll
    for (int off = 1; off < 256; off <<= 1) {
        if (par) { int x = sa[t] + (t >= off ? sa[t - off] : 0); sb[t] = x; }
        else     { int x = sb[t] + (t >= off ? sb[t - off] : 0); sa[t] = x; }
        par = !par;
        __syncthreads();
    }
    if (idx < NC3) rp3[idx] = sa[t] - v;
    if (t == 255) part[b] = sa[255];
    __threadfence();
    if (t == 0) lastBlk = (atomicAdd(ticket, 1) == gridDim.x - 1) ? 1 : 0;
    __syncthreads();
    if (!lastBlk) return;

    int run = 0;
    for (int j = 0; j < NB3; j += 256) {
        const int i2 = j + t;
        int pv = (i2 < NB3) ? atomicAdd(&part[i2], 0) : 0;
        sa[t] = pv;
        __syncthreads();
        bool p2 = true;
#pragma unroll
        for (int off = 1; off < 256; off <<= 1) {
            if (p2) { int x = sa[t] + (t >= off ? sa[t - off] : 0); sb[t] = x; }
            else    { int x = sb[t] + (t >= off ? sb[t - off] : 0); sa[t] = x; }
            p2 = !p2;
            __syncthreads();
        }
        if (i2 < NB3) part[i2] = run + sa[t] - pv;
        run += sa[255];
        __syncthreads();
    }
}

// ---- fill (r9-verified): rp3 doubles as cursor; boundary(idx+1) = rp3[idx]+part[idx>>8] ----
__device__ __forceinline__ void fill_body(
    int i, const int* __restrict__ e, int* __restrict__ rp3,
    const int* __restrict__ part, int* __restrict__ csr, int g, int f1)
{
    int src = f1 ? e[2 * i] : e[i];
    int dst = f1 ? e[2 * (N_EDGES + i)] : e[N_EDGES + i];
    int gidx = g * N_NODES + dst;
    int pos = part[gidx >> 8] + atomicAdd(&rp3[gidx], 1);
    csr[pos - g * N_EDGES] = src;
}

__global__ __launch_bounds__(256) void fill_k(
    const int* __restrict__ e, int* __restrict__ rp3, const int* __restrict__ part,
    int* __restrict__ csr, int g, const int* __restrict__ flags)
{
    fill_body(blockIdx.x * 256 + threadIdx.x, e, rp3, part, csr, g, flags[1]);
}

// ---- XCD-sliced gather: block's feature slice = blockIdx&7 -> XCD-local L2 working set ----
// K=256: slice=32 feats (4 chunks), 64 nodes/tile. K=128: slice=16 (2 chunks), 128 nodes/tile.
// EPI (L2 final): out = relu(mean + bias + hr2), written to d_out (fp32|bf16).
template<int K, bool EPI>
__global__ __launch_bounds__(256) void gather_slice(
    const unsigned short* __restrict__ hin,   // [N,K] bf16
    const int* __restrict__ rp3, const int* __restrict__ part,
    const int* __restrict__ csr_src, int gbase, int rbase,
    unsigned short* __restrict__ meanb,       // [N, stride 256] (non-EPI)
    const unsigned short* __restrict__ hr2,   // [N,128] (EPI)
    const unsigned short* __restrict__ bbv,   // [128]   (EPI)
    void* __restrict__ out,                   // [N,128] (EPI)
    const int* __restrict__ flags)
{
    constexpr int SLICE = K / 8;              // features per slice
    constexpr int CPS = SLICE / 8;            // uint4 chunks per slice
    constexpr int NPT = 256 / CPS;            // nodes per tile
    const int c = blockIdx.x & 7;             // XCD slice (HW round-robin hypothesis)
    const int t = blockIdx.x >> 3;
    const int tid = threadIdx.x;
    const int node = t * NPT + tid / CPS;
    if (node >= N_NODES) return;
    const int q = tid % CPS;
    const int fo = c * SLICE + q * 8;         // feature offset of this thread's 8 feats

    int i0 = gbase + node - 1;
    int beg = (i0 < 0) ? 0 : rp3[i0] + part[i0 >> 8];
    int i1 = gbase + node;
    int end = rp3[i1] + part[i1 >> 8];
    int deg = end - beg;
    const int* ix = csr_src + (beg - rbase);
    const unsigned short* col = hin + fo;

    float a[8], g[8];
#pragma unroll
    for (int v = 0; v < 8; ++v) { a[v] = 0.f; g[v] = 0.f; }
    int j = 0;
    for (; j + 3 < deg; j += 4) {
        int s0 = ix[j], s1 = ix[j + 1], s2 = ix[j + 2], s3 = ix[j + 3];
        uint4 v0 = *(const uint4*)(col + (size_t)s0 * K);
        uint4 v1 = *(const uint4*)(col + (size_t)s1 * K);
        uint4 v2 = *(const uint4*)(col + (size_t)s2 * K);
        uint4 v3 = *(const uint4*)(col + (size_t)s3 * K);
        acc8(a, v0); acc8(g, v1); acc8(a, v2); acc8(g, v3);
    }
    for (; j < deg; ++j) {
        uint4 v0 = *(const uint4*)(col + (size_t)ix[j] * K);
        acc8(a, v0);
    }
    const float inv = 1.0f / fmaxf((float)deg, 1.0f);

    if (EPI) {
        const size_t ro = (size_t)node * 128 + fo;
        uint4 hv = *(const uint4*)(hr2 + ro);
        uint4 bv = *(const uint4*)(bbv + fo);
        float h8[8], b8[8];
        h8[0] = bfbits2f(hv.x & 0xffffu); h8[1] = bfbits2f(hv.x >> 16);
        h8[2] = bfbits2f(hv.y & 0xffffu); h8[3] = bfbits2f(hv.y >> 16);
        h8[4] = bfbits2f(hv.z & 0xffffu); h8[5] = bfbits2f(hv.z >> 16);
        h8[6] = bfbits2f(hv.w & 0xffffu); h8[7] = bfbits2f(hv.w >> 16);
        b8[0] = bfbits2f(bv.x & 0xffffu); b8[1] = bfbits2f(bv.x >> 16);
        b8[2] = bfbits2f(bv.y & 0xffffu); b8[3] = bfbits2f(bv.y >> 16);
        b8[4] = bfbits2f(bv.z & 0xffffu); b8[5] = bfbits2f(bv.z >> 16);
        b8[6] = bfbits2f(bv.w & 0xffffu); b8[7] = bfbits2f(bv.w >> 16);
        float o8[8];
#pragma unroll
        for (int v = 0; v < 8; ++v) {
            float m = (a[v] + g[v]) * inv + b8[v] + h8[v];
            o8[v] = m > 0.f ? m : 0.f;
        }
        if (flags[0]) {
            float* op = (float*)out + ro;
            float4 o0 = { o8[0], o8[1], o8[2], o8[3] };
            float4 o1 = { o8[4], o8[5], o8[6], o8[7] };
            *(float4*)op = o0;
            *(float4*)(op + 4) = o1;
        } else {
            short8 t8;
#pragma unroll
            for (int v = 0; v < 8; ++v) t8[v] = (short)f2bfbits(o8[v]);
            *(short8*)((unsigned short*)out + ro) = t8;
        }
    } else {
        short8 t8;
#pragma unroll
        for (int v = 0; v < 8; ++v) t8[v] = (short)f2bfbits((a[v] + g[v]) * inv);
        *(short8*)(meanb + (size_t)node * 256 + fo) = t8;
    }
}

// ---- dual GEMM + bias + relu (r4-verified MFMA body), A0 from global (stride 256) ----
// In-place safe: A0 may alias hout's row-block (barrier between loads and stores).
// FILL=true: blocks [MG,2MG) run fill_body for graph gfill (overlap, r9 pattern).
template<int K, bool FILL>
__global__ __launch_bounds__(256) void gemm_dual(
    const unsigned short* __restrict__ A0,    // mean [N, stride 256], cols [0,K)
    const unsigned short* __restrict__ hin,   // self [N,K]
    const unsigned short* __restrict__ WlT,
    const unsigned short* __restrict__ WrT,
    const unsigned short* __restrict__ bbv,
    unsigned short* __restrict__ hout,        // [N,256]
    const int* __restrict__ e, int* __restrict__ rp3, const int* __restrict__ part,
    int* __restrict__ csr, int gfill, const int* __restrict__ flags)
{
    const int tid = threadIdx.x;
    if (FILL && blockIdx.x >= MG) {
        fill_body((blockIdx.x - MG) * 256 + tid, e, rp3, part, csr, gfill, flags[1]);
        return;
    }
    const int lane = tid & 63;
    const int wave = tid >> 6;
    const int r = lane & 15;
    const int quad = lane >> 4;
    const int m0 = blockIdx.x * 16;

    short8 a0f[K / 32], a1f[K / 32];
    const unsigned short* ap = A0 + (size_t)(m0 + r) * 256 + quad * 8;
#pragma unroll
    for (int k0 = 0; k0 < K / 32; ++k0)
        a0f[k0] = *(const short8*)(ap + k0 * 32);
    const unsigned short* hb = hin + (size_t)(m0 + r) * K + quad * 8;
#pragma unroll
    for (int k0 = 0; k0 < K / 32; ++k0)
        a1f[k0] = *(const short8*)(hb + k0 * 32);
    __syncthreads();     // in-place safety: all A0 reads of this row-block done before stores

    for (int nt = wave; nt < 16; nt += 4) {
        const int n0 = nt * 16;
        floatx4 acc = {0.f, 0.f, 0.f, 0.f};
        const unsigned short* b0 = WlT + (size_t)(n0 + r) * K + quad * 8;
        const unsigned short* b1 = WrT + (size_t)(n0 + r) * K + quad * 8;
#pragma unroll
        for (int k0 = 0; k0 < K / 32; ++k0)
            acc = __builtin_amdgcn_mfma_f32_16x16x32_bf16(a0f[k0], *(const short8*)(b0 + k0 * 32), acc, 0, 0, 0);
#pragma unroll
        for (int k0 = 0; k0 < K / 32; ++k0)
            acc = __builtin_amdgcn_mfma_f32_16x16x32_bf16(a1f[k0], *(const short8*)(b1 + k0 * 32), acc, 0, 0, 0);

        // C/D layout: col = lane&15, row = quad*4 + reg  [HW-verified]
        const int ccol = n0 + r;
        float bv = bfbits2f(bbv[ccol]);
#pragma unroll
        for (int i = 0; i < 4; ++i) {
            float v = acc[i] + bv;
            v = v > 0.f ? v : 0.f;
            hout[(size_t)(m0 + quad * 4 + i) * 256 + ccol] = f2bfbits(v);
        }
    }
}

// ---- L2 GEMM pair + fill(e2) merged (r9-verified) ----
__global__ __launch_bounds__(256) void gemm_fill(
    const unsigned short* __restrict__ A,
    const unsigned short* __restrict__ WT,
    unsigned short* __restrict__ out0,
    unsigned short* __restrict__ out1,
    const int* __restrict__ e2, int* __restrict__ rp3, const int* __restrict__ part,
    int* __restrict__ csr, const int* __restrict__ flags)
{
    const int tid = threadIdx.x;
    if (blockIdx.x >= MG) {
        fill_body((blockIdx.x - MG) * 256 + tid, e2, rp3, part, csr, 2, flags[1]);
        return;
    }
    const int lane = tid & 63, wave = tid >> 6;
    const int m0 = blockIdx.x * 16;
    const int r = lane & 15, quad = lane >> 4;
    short8 af[8];
    const unsigned short* ab = A + (size_t)(m0 + r) * 256 + quad * 8;
#pragma unroll
    for (int k0 = 0; k0 < 8; ++k0) af[k0] = *(const short8*)(ab + k0 * 32);

    for (int nt = wave; nt < 16; nt += 4) {
        const int n0 = nt * 16;
        floatx4 acc = {0.f, 0.f, 0.f, 0.f};
        const unsigned short* b0 = WT + (size_t)(n0 + r) * 256 + quad * 8;
#pragma unroll
        for (int k0 = 0; k0 < 8; ++k0)
            acc = __builtin_amdgcn_mfma_f32_16x16x32_bf16(af[k0], *(const short8*)(b0 + k0 * 32), acc, 0, 0, 0);
        const int ccol = n0 + r;
#pragma unroll
        for (int i = 0; i < 4; ++i) {
            const size_t row = m0 + quad * 4 + i;
            unsigned short v = f2bfbits(acc[i]);
            if (ccol < 128) out0[row * 128 + ccol] = v;
            else            out1[row * 128 + ccol - 128] = v;
        }
    }
}

// ---------------- orchestration ----------------
extern "C" void kernel_launch(void* const* d_in, const int* in_sizes, int n_in,
                              void* d_out, int out_size, void* d_ws, size_t ws_size,
                              hipStream_t stream) {
    const void* x  = d_in[0];
    const int* e[3] = { (const int*)d_in[1], (const int*)d_in[2], (const int*)d_in[3] };

    char* ws = (char*)d_ws;
    int* flags = (int*)ws;                                    // @0
    unsigned short* wt = (unsigned short*)(ws + 1024);        // 525,568 B -> 526,592
    unsigned short* bb0 = wt + 262144;
    unsigned short* bb1 = wt + 262400;
    unsigned short* bb2 = wt + 262656;
    int* rp3    = (int*)(ws + 526592);                        // 150,000 ints -> 1,126,592
    int* ticket = (int*)(ws + 1126592);                       // 1 int
    int* part   = (int*)(ws + 1126596);                       // 586 ints
    int* csr    = (int*)(ws + 1128960);                       // 3.2 MB -> 4,328,960
    unsigned short* hA = (unsigned short*)(ws + 4328960);     // 25.6 MB -> 29,928,960
    unsigned short* hB = (unsigned short*)(ws + 29928960);    // 25.6 MB -> 55,528,960 (55.5 MB, proven)
    // overlays (lifetime-disjoint):
    unsigned short* xb     = hB;              // x bf16; dead after L0 gemm
    unsigned short* meanb0 = hA;              // L0 mean [N, stride 256] — in-place with L0 gemm out (hA)
    unsigned short* meanb1 = hB;              // L1 mean — in-place with L1 gemm out (hB); kills xb
    unsigned short* hl2 = hA;                 // L2 pair outputs over dead hA
    unsigned short* hr2 = hA + (size_t)N_NODES * 128;

    // 1) zero counts + ticket
    hipMemsetAsync(rp3, 0, 600004, stream);
    // 2) detect-local prep + cvt + count3
    mega1<<<16653, 256, 0, stream>>>(d_in[4], d_in[6], d_in[7], d_in[9],
                                     d_in[10], d_in[12], d_in[5], d_in[8], d_in[11],
                                     wt, x, xb, e[0], e[1], e[2], rp3, flags);
    // 3) two-level scan
    scan12<<<NB3, 256, 0, stream>>>(rp3, part, ticket);
    // 4) fill graph0
    fill_k<<<EG, 256, 0, stream>>>(e[0], rp3, part, csr, 0, flags);
    // 5) L0 XCD-sliced gather: xb[.,128] -> meanb0 (hA, stride 256)
    gather_slice<128, false><<<391 * 8, 256, 0, stream>>>(
        xb, rp3, part, csr, 0, 0, meanb0, nullptr, nullptr, nullptr, flags);
    // 6) L0 dual GEMM (in-place hA) + fill graph1 overlapped
    gemm_dual<128, true><<<2 * MG, 256, 0, stream>>>(
        meanb0, xb, wt, wt + 32768, bb0, hA,
        e[1], rp3, part, csr, 1, flags);
    // 7) L1 XCD-sliced gather: hA[.,256] -> meanb1 (hB; xb dead)
    gather_slice<256, false><<<782 * 8, 256, 0, stream>>>(
        hA, rp3, part, csr, N_NODES, N_EDGES, meanb1, nullptr, nullptr, nullptr, flags);
    // 8) L1 dual GEMM (in-place hB)
    gemm_dual<256, false><<<MG, 256, 0, stream>>>(
        meanb1, hA, wt + 65536, wt + 131072, bb1, hB,
        nullptr, nullptr, nullptr, nullptr, 0, flags);
    // 9) L2 GEMM pair (hB -> hl2,hr2 over dead hA) + fill graph2 overlapped
    gemm_fill<<<2 * MG, 256, 0, stream>>>(hB, wt + 196608, hl2, hr2,
                                          e[2], rp3, part, csr, flags);
    // 10) L2 XCD-sliced gather + epilogue -> d_out
    gather_slice<128, true><<<391 * 8, 256, 0, stream>>>(
        hl2, rp3, part, csr, 2 * N_NODES, 2 * N_EDGES, nullptr, hr2, bb2, d_out, flags);
}

// Round 11
// 705.088 us; speedup vs baseline: 1.1803x; 1.1803x over previous
//
#include <hip/hip_runtime.h>
#include <hip/hip_bf16.h>
#include <stdint.h>

#define N_NODES 50000
#define N_EDGES 800000
#define NC3 150000               // 3 graphs x 50k counters
#define NB3 586                  // ceil(150000/256)
#define MG 3125                  // N_NODES/16 m-tiles
#define EG 3125                  // N_EDGES/256 edge blocks

typedef __attribute__((ext_vector_type(8))) short short8;
typedef __attribute__((ext_vector_type(4))) float floatx4;

__device__ __forceinline__ float bfbits2f(unsigned int u16) {
    union { unsigned int i; float f; } c; c.i = u16 << 16; return c.f;
}
__device__ __forceinline__ unsigned short f2bfbits(float f) {
    union { float f; unsigned int i; } c; c.f = f;
    unsigned int r = c.i + 0x7fffu + ((c.i >> 16) & 1u);   // RNE
    return (unsigned short)(r >> 16);
}
__device__ __forceinline__ void acc8(float* a, uint4 v) {
    a[0] += bfbits2f(v.x & 0xffffu); a[1] += bfbits2f(v.x >> 16);
    a[2] += bfbits2f(v.y & 0xffffu); a[3] += bfbits2f(v.y >> 16);
    a[4] += bfbits2f(v.z & 0xffffu); a[5] += bfbits2f(v.z >> 16);
    a[6] += bfbits2f(v.w & 0xffffu); a[7] += bfbits2f(v.w >> 16);
}

// A-fragment pointer into plane-major [8][N][K/8] buffer; contiguous short8.
template<int K>
__device__ __forceinline__ const short8* frag_ptr(
    const unsigned short* base, int m, int k0, int quad)
{
    if (K == 256)
        return (const short8*)(base + (size_t)k0 * (N_NODES * 32) + (size_t)m * 32 + quad * 8);
    else
        return (const short8*)(base + (size_t)(2 * k0 + (quad >> 1)) * (N_NODES * 16)
                               + (size_t)m * 16 + (quad & 1) * 8);
}

// ---- mega1: local detect + weight/bias prep + x->bf16 planes + count3 ----
__global__ __launch_bounds__(256) void mega1(
    const void* __restrict__ Wl0, const void* __restrict__ Wr0,
    const void* __restrict__ Wl1, const void* __restrict__ Wr1,
    const void* __restrict__ Wl2, const void* __restrict__ Wr2,
    const void* __restrict__ b0, const void* __restrict__ b1, const void* __restrict__ b2,
    unsigned short* __restrict__ wt,
    const void* __restrict__ x, unsigned short* __restrict__ xb,  // planes [8][N][16]
    const int* __restrict__ e0, const int* __restrict__ e1, const int* __restrict__ e2,
    int* __restrict__ rp3, int* __restrict__ flagsOut)
{
    __shared__ int s_cnt[2];
    const int t = threadIdx.x;
    if (t < 2) s_cnt[t] = 0;
    __syncthreads();
    {   // local detect (r2-verified logic)
        unsigned short v = ((const unsigned short*)x)[2 * t];
        int ex = (v >> 7) & 0xff;
        if (v == 0 || (ex >= 96 && ex <= 150)) atomicAdd(&s_cnt[0], 1);
        if (e0[2 * t + 1] != 0) atomicAdd(&s_cnt[1], 1);
    }
    __syncthreads();
    const int f0 = (s_cnt[0] < 200) ? 1 : 0;
    const int f1 = (s_cnt[1] < 128) ? 1 : 0;
    const int bid = blockIdx.x;

    if (bid == 16652) {
        if (t == 0) { flagsOut[0] = f0; flagsOut[1] = f1; }
        return;
    }
    if (bid >= 7277) {                       // count3
        int i = (bid - 7277) * 256 + t;
        int g = i / N_EDGES;
        int il = i - g * N_EDGES;
        const int* e = (g == 0) ? e0 : (g == 1) ? e1 : e2;
        int dst = f1 ? e[2 * (N_EDGES + il)] : e[N_EDGES + il];
        atomicAdd(&rp3[g * N_NODES + dst], 1);
        return;
    }
    if (bid >= 1027) {                       // cvt_x -> plane-major [8][N][16]
        int i = (bid - 1027) * 256 + t;      // handles cols [4j,4j+4) of node
        int node = i >> 5;
        int j = i & 31;
        uint2 o;
        if (f0) {
            float4 v = ((const float4*)x)[i];
            o.x = (unsigned int)f2bfbits(v.x) | ((unsigned int)f2bfbits(v.y) << 16);
            o.y = (unsigned int)f2bfbits(v.z) | ((unsigned int)f2bfbits(v.w) << 16);
        } else {
            o = ((const uint2*)x)[i];
        }
        *(uint2*)(xb + (size_t)(j >> 2) * (N_NODES * 16) + (size_t)node * 16 + (j & 3) * 4) = o;
        return;
    }
    if (bid >= 1024) {                       // biases
        const void* bs = bid == 1024 ? b0 : (bid == 1025 ? b1 : b2);
        unsigned short* bd = wt + 262144 + (bid - 1024) * 256;
        int n = (bid == 1026) ? 128 : 256;
        if (t < n) bd[t] = f0 ? f2bfbits(((const float*)bs)[t]) : ((const unsigned short*)bs)[t];
        return;
    }
    const void* W; unsigned short* WT; int K, N, off;
    if (bid < 128)      { W = Wl0; WT = wt;          K = 128; N = 256; off = bid; }
    else if (bid < 256) { W = Wr0; WT = wt + 32768;  K = 128; N = 256; off = bid - 128; }
    else if (bid < 512) { W = Wl1; WT = wt + 65536;  K = 256; N = 256; off = bid - 256; }
    else if (bid < 768) { W = Wr1; WT = wt + 131072; K = 256; N = 256; off = bid - 512; }
    else if (bid < 896) { W = Wl2; WT = wt + 196608; K = 256; N = 128; off = bid - 768; }
    else                { W = Wr2; WT = wt + 229376; K = 256; N = 128; off = bid - 896; }
    int idx = off * 256 + t;
    int k = idx / N, n = idx - k * N;
    unsigned short v = f0 ? f2bfbits(((const float*)W)[idx]) : ((const unsigned short*)W)[idx];
    WT[n * K + k] = v;
}

// ---- scan12 (r9-verified) ----
__global__ __launch_bounds__(256) void scan12(
    int* __restrict__ rp3, int* __restrict__ part, int* __restrict__ ticket)
{
    __shared__ int sa[256], sb[256];
    __shared__ int lastBlk;
    const int b = blockIdx.x, t = threadIdx.x, idx = b * 256 + t;
    int v = (idx < NC3) ? rp3[idx] : 0;
    sa[t] = v;
    __syncthreads();
    bool par = true;
#pragma unroll
    for (int off = 1; off < 256; off <<= 1) {
        if (par) { int x = sa[t] + (t >= off ? sa[t - off] : 0); sb[t] = x; }
        else     { int x = sb[t] + (t >= off ? sb[t - off] : 0); sa[t] = x; }
        par = !par;
        __syncthreads();
    }
    if (idx < NC3) rp3[idx] = sa[t] - v;
    if (t == 255) part[b] = sa[255];
    __threadfence();
    if (t == 0) lastBlk = (atomicAdd(ticket, 1) == gridDim.x - 1) ? 1 : 0;
    __syncthreads();
    if (!lastBlk) return;

    int run = 0;
    for (int j = 0; j < NB3; j += 256) {
        const int i2 = j + t;
        int pv = (i2 < NB3) ? atomicAdd(&part[i2], 0) : 0;
        sa[t] = pv;
        __syncthreads();
        bool p2 = true;
#pragma unroll
        for (int off = 1; off < 256; off <<= 1) {
            if (p2) { int x = sa[t] + (t >= off ? sa[t - off] : 0); sb[t] = x; }
            else    { int x = sb[t] + (t >= off ? sb[t - off] : 0); sa[t] = x; }
            p2 = !p2;
            __syncthreads();
        }
        if (i2 < NB3) part[i2] = run + sa[t] - pv;
        run += sa[255];
        __syncthreads();
    }
}

// ---- fill (r9-verified) ----
__device__ __forceinline__ void fill_body(
    int i, const int* __restrict__ e, int* __restrict__ rp3,
    const int* __restrict__ part, int* __restrict__ csr, int g, int f1)
{
    int src = f1 ? e[2 * i] : e[i];
    int dst = f1 ? e[2 * (N_EDGES + i)] : e[N_EDGES + i];
    int gidx = g * N_NODES + dst;
    int pos = part[gidx >> 8] + atomicAdd(&rp3[gidx], 1);
    csr[pos - g * N_EDGES] = src;
}

__global__ __launch_bounds__(256) void fill_k(
    const int* __restrict__ e, int* __restrict__ rp3, const int* __restrict__ part,
    int* __restrict__ csr, int g, const int* __restrict__ flags)
{
    fill_body(blockIdx.x * 256 + threadIdx.x, e, rp3, part, csr, g, flags[1]);
}

// ---- XCD-sliced gather over plane-major input, plane-major output (full-line writes) ----
// PC = plane cols (K/8). EPI: out = relu(mean + bias + hr2) -> d_out rows.
template<int PC, bool EPI>
__global__ __launch_bounds__(256) void gather_slice(
    const unsigned short* __restrict__ hin,   // planes [8][N][PC]
    const int* __restrict__ rp3, const int* __restrict__ part,
    const int* __restrict__ csr_src, int gbase, int rbase,
    unsigned short* __restrict__ outp,        // planes [8][N][PC] (non-EPI)
    const unsigned short* __restrict__ hr2,   // planes [8][N][16] (EPI)
    const unsigned short* __restrict__ bbv,   // [128] (EPI)
    void* __restrict__ out,                   // [N,128] rows (EPI)
    const int* __restrict__ flags)
{
    constexpr int CPS = PC / 8;               // uint4 chunks per plane-row
    constexpr int NPT = 256 / CPS;            // nodes per tile
    const int c = blockIdx.x & 7;             // XCD slice (round-robin heuristic)
    const int t = blockIdx.x >> 3;
    const int tid = threadIdx.x;
    const int node = t * NPT + tid / CPS;
    if (node >= N_NODES) return;
    const int q = (tid % CPS) * 8;            // short offset within plane row

    int i0 = gbase + node - 1;
    int beg = (i0 < 0) ? 0 : rp3[i0] + part[i0 >> 8];
    int i1 = gbase + node;
    int end = rp3[i1] + part[i1 >> 8];
    int deg = end - beg;
    const int* ix = csr_src + (beg - rbase);
    const unsigned short* pb = hin + (size_t)c * (N_NODES * PC) + q;

    float a[8], g[8];
#pragma unroll
    for (int v = 0; v < 8; ++v) { a[v] = 0.f; g[v] = 0.f; }
    int j = 0;
    for (; j + 3 < deg; j += 4) {
        int s0 = ix[j], s1 = ix[j + 1], s2 = ix[j + 2], s3 = ix[j + 3];
        uint4 v0 = *(const uint4*)(pb + (size_t)s0 * PC);
        uint4 v1 = *(const uint4*)(pb + (size_t)s1 * PC);
        uint4 v2 = *(const uint4*)(pb + (size_t)s2 * PC);
        uint4 v3 = *(const uint4*)(pb + (size_t)s3 * PC);
        acc8(a, v0); acc8(g, v1); acc8(a, v2); acc8(g, v3);
    }
    for (; j < deg; ++j) {
        uint4 v0 = *(const uint4*)(pb + (size_t)ix[j] * PC);
        acc8(a, v0);
    }
    const float inv = 1.0f / fmaxf((float)deg, 1.0f);

    if (EPI) {
        const unsigned short* hp = hr2 + (size_t)c * (N_NODES * 16) + (size_t)node * 16 + q;
        uint4 hv = *(const uint4*)hp;
        uint4 bv = *(const uint4*)(bbv + c * 16 + q);
        float h8[8], b8[8];
        h8[0] = bfbits2f(hv.x & 0xffffu); h8[1] = bfbits2f(hv.x >> 16);
        h8[2] = bfbits2f(hv.y & 0xffffu); h8[3] = bfbits2f(hv.y >> 16);
        h8[4] = bfbits2f(hv.z & 0xffffu); h8[5] = bfbits2f(hv.z >> 16);
        h8[6] = bfbits2f(hv.w & 0xffffu); h8[7] = bfbits2f(hv.w >> 16);
        b8[0] = bfbits2f(bv.x & 0xffffu); b8[1] = bfbits2f(bv.x >> 16);
        b8[2] = bfbits2f(bv.y & 0xffffu); b8[3] = bfbits2f(bv.y >> 16);
        b8[4] = bfbits2f(bv.z & 0xffffu); b8[5] = bfbits2f(bv.z >> 16);
        b8[6] = bfbits2f(bv.w & 0xffffu); b8[7] = bfbits2f(bv.w >> 16);
        float o8[8];
#pragma unroll
        for (int v = 0; v < 8; ++v) {
            float m = (a[v] + g[v]) * inv + b8[v] + h8[v];
            o8[v] = m > 0.f ? m : 0.f;
        }
        const size_t ro = (size_t)node * 128 + c * 16 + q;
        if (flags[0]) {
            float* op = (float*)out + ro;
            float4 o0 = { o8[0], o8[1], o8[2], o8[3] };
            float4 o1 = { o8[4], o8[5], o8[6], o8[7] };
            *(float4*)op = o0;
            *(float4*)(op + 4) = o1;
        } else {
            short8 t8;
#pragma unroll
            for (int v = 0; v < 8; ++v) t8[v] = (short)f2bfbits(o8[v]);
            *(short8*)((unsigned short*)out + ro) = t8;
        }
    } else {
        short8 t8;
#pragma unroll
        for (int v = 0; v < 8; ++v) t8[v] = (short)f2bfbits((a[v] + g[v]) * inv);
        *(short8*)(outp + (size_t)c * (N_NODES * PC) + (size_t)node * PC + q) = t8;
    }
}

// ---- dual GEMM + bias + relu; plane-major A0/A1 in, plane-major [8][N][32] out ----
// K=256 in-place legal: A0-read and out-write address sets coincide per block (barrier).
template<int K, bool FILL>
__global__ __launch_bounds__(256) void gemm_dual(
    const unsigned short* __restrict__ A0,    // mean planes [8][N][K/8]
    const unsigned short* __restrict__ hin,   // self planes [8][N][K/8]
    const unsigned short* __restrict__ WlT,
    const unsigned short* __restrict__ WrT,
    const unsigned short* __restrict__ bbv,
    unsigned short* __restrict__ hout,        // planes [8][N][32]
    const int* __restrict__ e, int* __restrict__ rp3, const int* __restrict__ part,
    int* __restrict__ csr, int gfill, const int* __restrict__ flags)
{
    const int tid = threadIdx.x;
    if (FILL && blockIdx.x >= MG) {
        fill_body((blockIdx.x - MG) * 256 + tid, e, rp3, part, csr, gfill, flags[1]);
        return;
    }
    const int lane = tid & 63;
    const int wave = tid >> 6;
    const int r = lane & 15;
    const int quad = lane >> 4;
    const int m0 = blockIdx.x * 16;

    short8 a0f[K / 32], a1f[K / 32];
#pragma unroll
    for (int k0 = 0; k0 < K / 32; ++k0) a0f[k0] = *frag_ptr<K>(A0, m0 + r, k0, quad);
#pragma unroll
    for (int k0 = 0; k0 < K / 32; ++k0) a1f[k0] = *frag_ptr<K>(hin, m0 + r, k0, quad);
    __syncthreads();     // in-place safety (L1): all A0 reads done before stores

    for (int nt = wave; nt < 16; nt += 4) {
        const int n0 = nt * 16;
        floatx4 acc = {0.f, 0.f, 0.f, 0.f};
        const unsigned short* b0 = WlT + (size_t)(n0 + r) * K + quad * 8;
        const unsigned short* b1 = WrT + (size_t)(n0 + r) * K + quad * 8;
#pragma unroll
        for (int k0 = 0; k0 < K / 32; ++k0)
            acc = __builtin_amdgcn_mfma_f32_16x16x32_bf16(a0f[k0], *(const short8*)(b0 + k0 * 32), acc, 0, 0, 0);
#pragma unroll
        for (int k0 = 0; k0 < K / 32; ++k0)
            acc = __builtin_amdgcn_mfma_f32_16x16x32_bf16(a1f[k0], *(const short8*)(b1 + k0 * 32), acc, 0, 0, 0);

        // C/D layout: col = lane&15, row = quad*4 + reg  [HW-verified]
        const int ccol = n0 + r;
        float bv = bfbits2f(bbv[ccol]);
        unsigned short* op = hout + (size_t)(ccol >> 5) * (N_NODES * 32) + (ccol & 31);
#pragma unroll
        for (int i = 0; i < 4; ++i) {
            float v = acc[i] + bv;
            v = v > 0.f ? v : 0.f;
            op[(size_t)(m0 + quad * 4 + i) * 32] = f2bfbits(v);
        }
    }
}

// ---- L2 GEMM pair (planes in, plane-16 outs) + fill(e2) overlap ----
__global__ __launch_bounds__(256) void gemm_fill(
    const unsigned short* __restrict__ A,     // hB planes [8][N][32]
    const unsigned short* __restrict__ WT,    // [256,256] = WlT2|WrT2
    unsigned short* __restrict__ out0,        // hl2 planes [8][N][16]
    unsigned short* __restrict__ out1,        // hr2 planes [8][N][16]
    const int* __restrict__ e2, int* __restrict__ rp3, const int* __restrict__ part,
    int* __restrict__ csr, const int* __restrict__ flags)
{
    const int tid = threadIdx.x;
    if (blockIdx.x >= MG) {
        fill_body((blockIdx.x - MG) * 256 + tid, e2, rp3, part, csr, 2, flags[1]);
        return;
    }
    const int lane = tid & 63, wave = tid >> 6;
    const int m0 = blockIdx.x * 16;
    const int r = lane & 15, quad = lane >> 4;
    short8 af[8];
#pragma unroll
    for (int k0 = 0; k0 < 8; ++k0) af[k0] = *frag_ptr<256>(A, m0 + r, k0, quad);

    for (int nt = wave; nt < 16; nt += 4) {
        const int n0 = nt * 16;
        floatx4 acc = {0.f, 0.f, 0.f, 0.f};
        const unsigned short* b0 = WT + (size_t)(n0 + r) * 256 + quad * 8;
#pragma unroll
        for (int k0 = 0; k0 < 8; ++k0)
            acc = __builtin_amdgcn_mfma_f32_16x16x32_bf16(af[k0], *(const short8*)(b0 + k0 * 32), acc, 0, 0, 0);
        const int ccol = n0 + r;
        const int c2 = ccol & 127;
        unsigned short* op = (ccol < 128 ? out0 : out1)
                             + (size_t)(c2 >> 4) * (N_NODES * 16) + (c2 & 15);
#pragma unroll
        for (int i = 0; i < 4; ++i) {
            unsigned short v = f2bfbits(acc[i]);
            op[(size_t)(m0 + quad * 4 + i) * 16] = v;
        }
    }
}

// ---------------- orchestration ----------------
extern "C" void kernel_launch(void* const* d_in, const int* in_sizes, int n_in,
                              void* d_out, int out_size, void* d_ws, size_t ws_size,
                              hipStream_t stream) {
    const void* x  = d_in[0];
    const int* e[3] = { (const int*)d_in[1], (const int*)d_in[2], (const int*)d_in[3] };

    char* ws = (char*)d_ws;
    int* flags = (int*)ws;                                    // @0
    unsigned short* wt = (unsigned short*)(ws + 1024);        // 525,568 B -> 526,592
    unsigned short* bb0 = wt + 262144;
    unsigned short* bb1 = wt + 262400;
    unsigned short* bb2 = wt + 262656;
    int* rp3    = (int*)(ws + 526592);                        // 150,000 ints -> 1,126,592
    int* ticket = (int*)(ws + 1126592);
    int* part   = (int*)(ws + 1126596);
    int* csr    = (int*)(ws + 1128960);                       // 3.2 MB -> 4,328,960
    unsigned short* hA = (unsigned short*)(ws + 4328960);     // 25.6 MB planes [8][N][32]
    unsigned short* hB = (unsigned short*)(ws + 29928960);    // 25.6 MB -> 55,528,960 (55.5 MB, proven)
    // overlays (lifetime-disjoint), all plane-major:
    unsigned short* xb     = hB;                              // [8][N][16] 12.8 MB; dead after L0 gemm
    unsigned short* meanb0 = hB + 6400000;                    // [8][N][16] 12.8 MB; dead after L0 gemm
    unsigned short* meanb1 = hB;                              // [8][N][32] in-place with hB out (L1)
    unsigned short* hl2 = hA;                                 // [8][N][16]; hA dead after L1 gemm
    unsigned short* hr2 = hA + 6400000;                       // [8][N][16]

    // 1) zero counts + ticket
    hipMemsetAsync(rp3, 0, 600004, stream);
    // 2) detect-local prep + cvt(planes) + count3
    mega1<<<16653, 256, 0, stream>>>(d_in[4], d_in[6], d_in[7], d_in[9],
                                     d_in[10], d_in[12], d_in[5], d_in[8], d_in[11],
                                     wt, x, xb, e[0], e[1], e[2], rp3, flags);
    // 3) two-level scan
    scan12<<<NB3, 256, 0, stream>>>(rp3, part, ticket);
    // 4) fill graph0
    fill_k<<<EG, 256, 0, stream>>>(e[0], rp3, part, csr, 0, flags);
    // 5) L0 gather: xb planes -> meanb0 planes
    gather_slice<16, false><<<391 * 8, 256, 0, stream>>>(
        xb, rp3, part, csr, 0, 0, meanb0, nullptr, nullptr, nullptr, flags);
    // 6) L0 dual GEMM -> hA planes, + fill graph1 overlapped
    gemm_dual<128, true><<<2 * MG, 256, 0, stream>>>(
        meanb0, xb, wt, wt + 32768, bb0, hA,
        e[1], rp3, part, csr, 1, flags);
    // 7) L1 gather: hA planes -> meanb1 planes (clobbers xb/meanb0 — dead)
    gather_slice<32, false><<<782 * 8, 256, 0, stream>>>(
        hA, rp3, part, csr, N_NODES, N_EDGES, meanb1, nullptr, nullptr, nullptr, flags);
    // 8) L1 dual GEMM in-place -> hB planes
    gemm_dual<256, false><<<MG, 256, 0, stream>>>(
        meanb1, hA, wt + 65536, wt + 131072, bb1, hB,
        nullptr, nullptr, nullptr, nullptr, 0, flags);
    // 9) L2 GEMM pair -> hl2/hr2 planes (over dead hA), + fill graph2 overlapped
    gemm_fill<<<2 * MG, 256, 0, stream>>>(hB, wt + 196608, hl2, hr2,
                                          e[2], rp3, part, csr, flags);
    // 10) L2 gather + epilogue -> d_out rows
    gather_slice<16, true><<<391 * 8, 256, 0, stream>>>(
        hl2, rp3, part, csr, 2 * N_NODES, 2 * N_EDGES, nullptr, hr2, bb2, d_out, flags);
}